// Round 9
// baseline (272.985 us; speedup 1.0000x reference)
//
#include <hip/hip_runtime.h>
#include <hip/hip_bf16.h>

#define NN      50000
#define INDIM   512
#define HIDDEN  256
#define NE      800000
#define BIASF   0.0001f

typedef __attribute__((ext_vector_type(4))) float  f32x4;
typedef __attribute__((ext_vector_type(4))) __bf16 bf16x4;
typedef __attribute__((ext_vector_type(8))) __bf16 bf16x8;

// async global->LDS DMA, 16 B per lane, lds dest = wave-uniform base + lane*16
__device__ __forceinline__ void async_copy16(const float* gp, const float* lp) {
    __builtin_amdgcn_global_load_lds(
        (const __attribute__((address_space(1))) void*)gp,
        (__attribute__((address_space(3))) void*)lp,
        16, 0, 0);
}

// ---------------------------------------------------------------------------
// prep: blocks 0..31 : Wtb[n][k] = (bf16)W_emb[k][n] via coalesced LDS transpose
//       block  32    : w_sym[j] = 0.5*(We[j]+We[j+256])
// ---------------------------------------------------------------------------
__global__ __launch_bounds__(256) void prep_kernel(const float* __restrict__ W_emb,
                                                   const float* __restrict__ W_edge,
                                                   __bf16* __restrict__ Wtb,
                                                   float* __restrict__ w_sym) {
    const int b   = blockIdx.x;
    const int tid = threadIdx.x;
    if (b < 32) {
        __shared__ float t[64 * 65];
        const int kt = (b >> 2) * 64;
        const int nt = (b & 3) * 64;
        const int rr = tid >> 4;           // 0..15
        const int cc = (tid & 15) * 4;     // 0..60
#pragma unroll
        for (int p = 0; p < 4; ++p) {
            int r = p * 16 + rr;
            f32x4 v = *(const f32x4*)&W_emb[(size_t)(kt + r) * HIDDEN + nt + cc];
            t[(cc + 0) * 65 + r] = v[0];
            t[(cc + 1) * 65 + r] = v[1];
            t[(cc + 2) * 65 + r] = v[2];
            t[(cc + 3) * 65 + r] = v[3];
        }
        __syncthreads();
#pragma unroll
        for (int p = 0; p < 4; ++p) {
            int n = p * 16 + rr;
            bf16x4 o;
            o[0] = (__bf16)t[n * 65 + cc + 0];
            o[1] = (__bf16)t[n * 65 + cc + 1];
            o[2] = (__bf16)t[n * 65 + cc + 2];
            o[3] = (__bf16)t[n * 65 + cc + 3];
            *(bf16x4*)&Wtb[(size_t)(nt + n) * INDIM + kt + cc] = o;
        }
    } else {
        w_sym[tid] = 0.5f * (W_edge[tid] + W_edge[tid + HIDDEN]);
    }
}

// ---------------------------------------------------------------------------
// Barrier-free wave-private GEMM + fused node-dot:
//   g[m] = sum_n relu(emb[m]@W[:,n] + b[n]) * w_sym[n]
// Each WAVE owns 16 rows x all 256 cols (acc = 16 x f32x4). A is staged
// wave-privately: chunk = K=32 (16 rows x 128 B = 2 DMA instrs), 4 LDS
// slots/wave, issued 3 chunks ahead, synced by explicit s_waitcnt vmcnt(N)
// (constant immediates via macro-expanded K-steps). NO __syncthreads, so
// waves drift freely and the CU memory pipe is fed continuously (r5-r7's
// barrier drains delivered only ~2.5 B/cyc/CU vs ~52 B/cyc DMA capability).
// vmcnt(N) waits for oldest outstanding [m135]: chunk ks always has >=6
// younger VM ops after it, so vmcnt(2*min(3,15-ks)) guarantees it landed
// even with compiler-interleaved B loads (those only strengthen the wait).
// B: bf16x8 fragments direct from the 256 KB L1/L2-hot Wtb, imm offsets.
// Epilogue wave-local (xor-reduce over ml lanes, direct g store).
// ---------------------------------------------------------------------------
__global__ __launch_bounds__(256, 2) void gemm_g_kernel(const float* __restrict__ A,
                                                        const __bf16* __restrict__ Wtb,
                                                        const float* __restrict__ bias,
                                                        const float* __restrict__ w_sym,
                                                        float* __restrict__ g) {
    // per wave: 4 slots x 2 groups x 264 dwords (8 rows x 32 f32 + 8 pad)
    __shared__ __align__(16) float Abuf[4 * 4 * 2 * 264];   // 33,792 B

    const int tid  = threadIdx.x;
    const int lane = tid & 63;
    const int w    = tid >> 6;
    const int ml   = lane & 15, kq = lane >> 4;
    const int tile = blockIdx.x * 4 + w;          // wave tile id (16 rows)
    if (tile >= 3125) return;                     // 782*4 = 3128 slots, 3 idle
    const int m0   = tile * 16;                   // rows m0..m0+15 (50000 exact)

    float* wbuf = Abuf + w * (4 * 2 * 264);

    // DMA source pattern: lane L -> row (L>>3), k = (L&7)*4 within chunk
    const float* gsrc0 = A + (size_t)(m0 + (lane >> 3)) * INDIM + (lane & 7) * 4;
    const float* gsrc1 = gsrc0 + 8 * INDIM;       // rows +8

    // prologue: stage chunks 0,1,2 into slots 0,1,2 (6 DMAs)
#pragma unroll
    for (int c = 0; c < 3; ++c) {
        async_copy16(gsrc0 + c * 32, wbuf + c * 528);
        async_copy16(gsrc1 + c * 32, wbuf + c * 528 + 264);
    }

    const __bf16* bp = Wtb + (size_t)ml * INDIM + kq * 8;   // + nt*16*INDIM imm

    f32x4 acc[16];
#pragma unroll
    for (int nt = 0; nt < 16; ++nt) acc[nt] = (f32x4)0.0f;

    const float* afrag_base = wbuf + (ml >> 3) * 264 + (ml & 7) * 32 + kq * 8;

    // one K-step; ks is a LITERAL -> waitcnt immediates are constant exprs
#define KSTEP(ks)                                                              \
    {                                                                          \
        if ((ks) + 3 < 16) {                                                   \
            __builtin_amdgcn_s_waitcnt(0xC07F); /* lgkmcnt(0): slot reads done */ \
            async_copy16(gsrc0 + ((ks) + 3) * 32,                              \
                         wbuf + (((ks) + 3) & 3) * 528);                       \
            async_copy16(gsrc1 + ((ks) + 3) * 32,                              \
                         wbuf + (((ks) + 3) & 3) * 528 + 264);                 \
        }                                                                      \
        /* chunk ks landed: <= 2*min(3,15-ks) younger A-DMAs outstanding */    \
        __builtin_amdgcn_s_waitcnt(                                            \
            0xF70 | (2 * ((15 - (ks)) < 3 ? (15 - (ks)) : 3)));                \
        const float* lf = afrag_base + ((ks) & 3) * 528;                       \
        f32x4 lo = *(const f32x4*)lf;                                          \
        f32x4 hi = *(const f32x4*)(lf + 4);                                    \
        bf16x8 af;                                                             \
        af[0] = (__bf16)lo[0]; af[1] = (__bf16)lo[1];                          \
        af[2] = (__bf16)lo[2]; af[3] = (__bf16)lo[3];                          \
        af[4] = (__bf16)hi[0]; af[5] = (__bf16)hi[1];                          \
        af[6] = (__bf16)hi[2]; af[7] = (__bf16)hi[3];                          \
        bf16x8 bfr[16];                                                        \
        _Pragma("unroll")                                                      \
        for (int nt = 0; nt < 16; ++nt)                                        \
            bfr[nt] = *(const bf16x8*)(bp + nt * 16 * INDIM + (ks) * 32);      \
        _Pragma("unroll")                                                      \
        for (int nt = 0; nt < 16; ++nt)                                        \
            acc[nt] = __builtin_amdgcn_mfma_f32_16x16x32_bf16(                 \
                af, bfr[nt], acc[nt], 0, 0, 0);                                \
    }

    KSTEP(0)  KSTEP(1)  KSTEP(2)  KSTEP(3)
    KSTEP(4)  KSTEP(5)  KSTEP(6)  KSTEP(7)
    KSTEP(8)  KSTEP(9)  KSTEP(10) KSTEP(11)
    KSTEP(12) KSTEP(13) KSTEP(14) KSTEP(15)
#undef KSTEP

    // ---- epilogue (wave-local): relu + dot w_sym over all 256 cols,
    //      xor-reduce over the 16 ml lanes, direct store of 16 rows.
    //      C/D layout: col = nt*16+ml, row = kq*4 + r  [verified m89/m91]
    float wsv[16], bcv[16];
#pragma unroll
    for (int nt = 0; nt < 16; ++nt) {
        int col = nt * 16 + ml;
        wsv[nt] = w_sym[col];
        bcv[nt] = bias[col];
    }
#pragma unroll
    for (int r = 0; r < 4; ++r) {
        float s = 0.0f;
#pragma unroll
        for (int nt = 0; nt < 16; ++nt) {
            float x = acc[nt][r] + bcv[nt];
            s = fmaf(fmaxf(x, 0.0f), wsv[nt], s);
        }
        s += __shfl_xor(s, 1);
        s += __shfl_xor(s, 2);
        s += __shfl_xor(s, 4);
        s += __shfl_xor(s, 8);
        if (ml == 0) g[m0 + kq * 4 + r] = s;
    }
}

// ---------------------------------------------------------------------------
// edge kernel: one THREAD per edge; g gathers are 4B hits in a 200 KB array.
// ---------------------------------------------------------------------------
__global__ __launch_bounds__(256) void edge_kernel(const float* __restrict__ g,
                                                   const int* __restrict__ edges,
                                                   const float* __restrict__ u,
                                                   const float* __restrict__ b_edge,
                                                   float* __restrict__ out) {
    const int e  = blockIdx.x * 256 + threadIdx.x;      // NE = 3125*256 exactly
    const int i0 = edges[e];
    const int i1 = edges[NE + e];
    float raw = g[i0] + g[i1] + b_edge[0];
    float uu  = u[e];
    float eps = fmaf(uu, BIASF - (1.0f - BIASF), 1.0f - BIASF); // -0.9998u+0.9999
    float gt  = logf(eps) - log1pf(-eps) + raw;                 // TEMPERATURE=1
    out[e] = 1.0f / (1.0f + expf(-gt));
}

// ---------------------------------------------------------------------------
extern "C" void kernel_launch(void* const* d_in, const int* in_sizes, int n_in,
                              void* d_out, int out_size, void* d_ws, size_t ws_size,
                              hipStream_t stream) {
    const float* embedding = (const float*)d_in[0];
    const int*   edges     = (const int*)d_in[1];
    const float* u         = (const float*)d_in[2];
    const float* W_emb     = (const float*)d_in[3];
    const float* b_emb     = (const float*)d_in[4];
    const float* W_edge    = (const float*)d_in[5];
    const float* b_edge    = (const float*)d_in[6];
    float*       out       = (float*)d_out;

    // workspace layout
    char*   ws    = (char*)d_ws;
    __bf16* Wtb   = (__bf16*)ws;                      // 262,144 B
    float*  w_sym = (float*)(ws + 262144);            //   1,024 B
    float*  g     = (float*)(ws + 262144 + 1024);     // 200,000 B

    prep_kernel<<<33, 256, 0, stream>>>(W_emb, W_edge, Wtb, w_sym);

    gemm_g_kernel<<<782, 256, 0, stream>>>(embedding, Wtb, b_emb, w_sym, g);

    edge_kernel<<<NE / 256, 256, 0, stream>>>(g, edges, u, b_edge, out);
}